// Round 14
// baseline (1406.015 us; speedup 1.0000x reference)
//
#include <hip/hip_runtime.h>

// SO(2)-equivariant edge conv — bf16 MFMA pipeline, round 14.
// X per edge (2432 bf16): m0 rows0-4 [0,640) | m1 re+im [640,1664) | m2 [1664,2432)
// Zr per edge (1536-short stride): conv1 out [0,1216) + sigmoid gates [1216,1472)
// Y2 per edge (1216 bf16). Weights transposed [N][K] bf16, N padded to 128, complex folded.
// r14: LDS-free register GEMM — one wave per 64x64 output tile, A+B fragments loaded
// straight from (XCD-pinned, L2-hot) global into registers. Zero barriers, zero LDS,
// 64-thread blocks, VGPR-limited occupancy ~2x. LDS traffic (the largest pipe term
// in r13's accounting) eliminated; 2x duplicated L2 reads stay under the L2 ceiling.

typedef __attribute__((ext_vector_type(8))) short bf16x8;
typedef __attribute__((ext_vector_type(4))) float f32x4;

union U8 { uint4 v; unsigned short s[8]; };

__device__ __forceinline__ unsigned short f2b(float f) {
    unsigned u = __float_as_uint(f);
    unsigned r = (u + 0x7FFFu + ((u >> 16) & 1u)) >> 16;
    return (unsigned short)r;
}
__device__ __forceinline__ float b2f(unsigned short h) {
    return __uint_as_float(((unsigned)h) << 16);
}
__device__ __forceinline__ float sigm_(float x){ return 1.0f/(1.0f+__expf(-x)); }
__device__ __forceinline__ float silu_(float x){ return x/(1.0f+__expf(-x)); }

// weight region offsets (bf16 elems) in ws — N padded to multiples of 128
#define OFF_W1T   0L         // [640][640]  real N=576
#define OFF_W1C1  409600L    // [512][1024]
#define OFF_W1C2  933888L    // [512][768]  real N=384
#define OFF_V0T   1327104L   // [384][320]  real N=320
#define OFF_V1C   1449984L   // [512][512]
#define OFF_V2C   1712128L   // [512][384]  real N=384
#define OFF_RW2T  1908736L   // [1536][64]
#define W_TOTAL   2007040L
#define NNODES    2500
#define NFT_ELEMS (2500L * 2048L)

// ---------------- weight prep: f32 -> bf16, transpose [N][K], fold complex, pad N ----
__global__ void k_prep(const float* __restrict__ w1m0, const float* __restrict__ w1r1,
                       const float* __restrict__ w1i1, const float* __restrict__ w1r2,
                       const float* __restrict__ w1i2, const float* __restrict__ w2m0,
                       const float* __restrict__ w2r1, const float* __restrict__ w2i1,
                       const float* __restrict__ w2r2, const float* __restrict__ w2i2,
                       const float* __restrict__ rw2, short* __restrict__ W)
{
    long i = (long)blockIdx.x * blockDim.x + threadIdx.x;
    if (i >= W_TOTAL) return;
    float v;
    if (i < OFF_W1C1) {                    // W1T [640][640] real 576
        int n = (int)(i / 640), k = (int)(i % 640);
        v = (n < 576) ? w1m0[k * 576 + n] : 0.f;
    } else if (i < OFF_W1C2) {             // W1c1 [512][1024]
        long j = i - OFF_W1C1; int n = (int)(j >> 10), k = (int)(j & 1023);
        v = (n < 256) ? ((k < 512) ? w1r1[k*256 + n] : -w1i1[(k-512)*256 + n])
                      : ((k < 512) ? w1i1[k*256 + (n-256)] : w1r1[(k-512)*256 + (n-256)]);
    } else if (i < OFF_V0T) {              // W1c2 [512][768] real 384
        long j = i - OFF_W1C2; int n = (int)(j / 768), k = (int)(j % 768);
        v = (n >= 384) ? 0.f
          : (n < 192) ? ((k < 384) ? w1r2[k*192 + n] : -w1i2[(k-384)*192 + n])
                      : ((k < 384) ? w1i2[k*192 + (n-192)] : w1r2[(k-384)*192 + (n-192)]);
    } else if (i < OFF_V1C) {              // V0T [384][320] real 320
        long j = i - OFF_V0T; int n = (int)(j / 320), k = (int)(j % 320);
        v = (n < 320) ? w2m0[k * 320 + n] : 0.f;
    } else if (i < OFF_V2C) {              // V1c [512][512]
        long j = i - OFF_V1C; int n = (int)(j >> 9), k = (int)(j & 511);
        v = (n < 256) ? ((k < 256) ? w2r1[k*256 + n] : -w2i1[(k-256)*256 + n])
                      : ((k < 256) ? w2i1[k*256 + (n-256)] : w2r1[(k-256)*256 + (n-256)]);
    } else if (i < OFF_RW2T) {             // V2c [512][384] real 384
        long j = i - OFF_V2C; int n = (int)(j / 384), k = (int)(j % 384);
        v = (n >= 384) ? 0.f
          : (n < 192) ? ((k < 192) ? w2r2[k*192 + n] : -w2i2[(k-192)*192 + n])
                      : ((k < 192) ? w2i2[k*192 + (n-192)] : w2r2[(k-192)*192 + (n-192)]);
    } else {                               // RW2T [1536][64]
        long j = i - OFF_RW2T; int n = (int)(j >> 6), d = (int)(j & 63);
        v = rw2[d * 1536 + n];
    }
    W[i] = (short)f2b(v);
}

// ---------------- node-feature transpose ----------------
__global__ __launch_bounds__(256)
void k_nft(const float* __restrict__ nf, short* __restrict__ nfT)
{
    __shared__ float s_nf[25 * 65];
    const int t = threadIdx.x;
    const long nn = blockIdx.x;
    for (int p = t; p < 1600; p += 256) {
        int r = p >> 6, c = p & 63;
        s_nf[r * 65 + c] = nf[nn * 1600 + p];
    }
    __syncthreads();
    for (int i = t; i < 2048; i += 256) {
        int c = i >> 5, k = i & 31;
        float v = (k < 25) ? s_nf[k * 65 + c] : 0.f;
        nfT[nn * 2048 + i] = (short)f2b(v);
    }
}

// ---------------- CSR build ----------------
__global__ void k_hist(const int* __restrict__ rcv, int* __restrict__ cnt, long e0, long n)
{
    long e = (long)blockIdx.x * 256 + threadIdx.x;
    if (e < n) atomicAdd(&cnt[rcv[e0 + e]], 1);
}

__global__ __launch_bounds__(256)
void k_scan(const int* __restrict__ cnt, int* __restrict__ off, int* __restrict__ nxt)
{
    __shared__ int part[256];
    const int t = threadIdx.x;
    const int base = t * 10;
    int loc[10]; int s = 0;
    #pragma unroll
    for (int j = 0; j < 10; ++j) {
        int idx = base + j;
        int v = (idx < NNODES) ? cnt[idx] : 0;
        loc[j] = s; s += v;
    }
    part[t] = s;
    __syncthreads();
    for (int d = 1; d < 256; d <<= 1) {
        int v = part[t];
        int u = (t >= d) ? part[t - d] : 0;
        __syncthreads();
        part[t] = v + u;
        __syncthreads();
    }
    int excl = (t == 0) ? 0 : part[t - 1];
    #pragma unroll
    for (int j = 0; j < 10; ++j) {
        int idx = base + j;
        if (idx < NNODES) { int o = excl + loc[j]; off[idx] = o; nxt[idx] = o; }
    }
}

__global__ void k_scat(const int* __restrict__ rcv, int* __restrict__ nxt,
                       int* __restrict__ perm, long e0, long n)
{
    long e = (long)blockIdx.x * 256 + threadIdx.x;
    if (e < n) {
        int p = atomicAdd(&nxt[rcv[e0 + e]], 1);
        perm[p] = (int)e;
    }
}

// ---------------- radial MLP ----------------
__global__ __launch_bounds__(512)
void k_rad(const float* __restrict__ ee, const float* __restrict__ rw1,
           const float* __restrict__ rb1, const float* __restrict__ rb2,
           const short* __restrict__ RW2T, short* __restrict__ rad,
           long e0, long Etot)
{
    __shared__ __align__(16) short s_h[32 * 64];
    const int t = threadIdx.x, w = t >> 6, l = t & 63, l15 = l & 15, lhi = l >> 4;
    const long eb = (long)blockIdx.x * 32;

    #pragma unroll
    for (int j = 0; j < 4; ++j) {
        int i = t + j * 512;
        int e = i >> 6, d = i & 63;
        long ge = e0 + eb + e;
        float a = rb1[d];
        if (ge < Etot) {
            const float* ep = ee + ge * 128;
            #pragma unroll 16
            for (int dd = 0; dd < 128; ++dd) a = fmaf(ep[dd], rw1[dd * 64 + d], a);
            a = silu_(a);
        } else a = 0.f;
        *(short*)((char*)s_h + e * 128 + ((d * 2) ^ ((e & 7) << 4))) = (short)f2b(a);
    }
    __syncthreads();

    f32x4 acc[6][2][2];
    #pragma unroll
    for (int g = 0; g < 6; ++g)
        #pragma unroll
        for (int mt = 0; mt < 2; ++mt)
            #pragma unroll
            for (int nt = 0; nt < 2; ++nt)
                acc[g][mt][nt] = (f32x4){0.f, 0.f, 0.f, 0.f};

    #pragma unroll
    for (int ks = 0; ks < 2; ++ks) {
        bf16x8 af[2];
        #pragma unroll
        for (int mt = 0; mt < 2; ++mt)
            af[mt] = *(const bf16x8*)((const char*)s_h + (mt * 16 + l15) * 128 +
                                      (((ks << 6) + (lhi << 4)) ^ ((l & 7) << 4)));
        #pragma unroll
        for (int g = 0; g < 6; ++g) {
            int grp = w + g * 8;
            #pragma unroll
            for (int nt = 0; nt < 2; ++nt) {
                int col = grp * 32 + nt * 16 + l15;
                bf16x8 bf = *(const bf16x8*)(RW2T + (long)col * 64 + (ks << 5) + (lhi << 3));
                #pragma unroll
                for (int mt = 0; mt < 2; ++mt)
                    acc[g][mt][nt] = __builtin_amdgcn_mfma_f32_16x16x32_bf16(af[mt], bf, acc[g][mt][nt], 0, 0, 0);
            }
        }
    }
    #pragma unroll
    for (int g = 0; g < 6; ++g)
        #pragma unroll
        for (int nt = 0; nt < 2; ++nt) {
            int col = (w + g * 8) * 32 + nt * 16 + l15;
            float bias = rb2[col];
            #pragma unroll
            for (int mt = 0; mt < 2; ++mt)
                #pragma unroll
                for (int r = 0; r < 4; ++r) {
                    int e = mt * 16 + lhi * 4 + r;
                    rad[(eb + e) * 1536 + col] = (short)f2b(acc[g][mt][nt][r] + bias);
                }
        }
}

// ---------------- MFMA wigner rotate, vectorized writeout ----------------
__global__ __launch_bounds__(256)
void k_rot2(const float* __restrict__ wig, const short* __restrict__ nfT,
            const short* __restrict__ rad,
            const int* __restrict__ snd, const int* __restrict__ rcv,
            short* __restrict__ X, long e0, long nchunk)
{
    __shared__ float s_wg[4][480];
    __shared__ __align__(16) short s_rot[4][20 * 128];
    const int t = threadIdx.x, w = t >> 6, l = t & 63, l15 = l & 15, lhi = l >> 4;
    const long eb = (long)blockIdx.x * 4;
    const long el = eb + w;
    const bool valid = (el < nchunk);

    for (int p = t; p < 4 * 475; p += 256) {
        int e = p / 475, q = p - e * 475;
        if (eb + e < nchunk) s_wg[e][q] = wig[(e0 + eb + e) * 475 + q];
    }
    __syncthreads();

    if (valid) {
        long ge = e0 + el;
        int n0 = snd[ge], n1 = rcv[ge];
        U8 a0u, a1u;
        #pragma unroll
        for (int j = 0; j < 8; ++j) {
            int k = lhi * 8 + j;
            a0u.s[j] = (k < 25) ? f2b(s_wg[w][l15 * 25 + k]) : (unsigned short)0;
            a1u.s[j] = (l15 < 3 && k < 25) ? f2b(s_wg[w][(16 + l15) * 25 + k]) : (unsigned short)0;
        }
        bf16x8 a0 = *(bf16x8*)&a0u, a1 = *(bf16x8*)&a1u;

        f32x4 acc0[8], acc1[8];
        #pragma unroll
        for (int nt = 0; nt < 8; ++nt) {
            acc0[nt] = (f32x4){0.f, 0.f, 0.f, 0.f};
            acc1[nt] = (f32x4){0.f, 0.f, 0.f, 0.f};
        }
        #pragma unroll
        for (int nt = 0; nt < 8; ++nt) {
            int col = nt * 16 + l15;
            bf16x8 b = *(const bf16x8*)(nfT + (long)(col < 64 ? n0 : n1) * 2048 +
                                        (long)(col & 63) * 32 + (lhi << 3));
            acc0[nt] = __builtin_amdgcn_mfma_f32_16x16x32_bf16(a0, b, acc0[nt], 0, 0, 0);
            acc1[nt] = __builtin_amdgcn_mfma_f32_16x16x32_bf16(a1, b, acc1[nt], 0, 0, 0);
        }
        char* base = (char*)s_rot[w];
        #pragma unroll
        for (int nt = 0; nt < 8; ++nt) {
            int col2 = (nt * 16 + l15) * 2;
            #pragma unroll
            for (int r = 0; r < 4; ++r) {
                int row = lhi * 4 + r;
                *(short*)(base + ((row * 256 + col2) ^ ((row & 7) << 4))) = (short)f2b(acc0[nt][r]);
            }
            if (lhi == 0) {
                #pragma unroll
                for (int r = 0; r < 4; ++r) {
                    int row = 16 + r;
                    *(short*)(base + ((row * 256 + col2) ^ ((row & 7) << 4))) = (short)f2b(acc1[nt][r]);
                }
            }
        }
    }
    __syncthreads();

    short* xp = X + el * 2432;
    if (valid) {
        const short* rp = rad + el * 1536;
        #pragma unroll
        for (int it = 0; it < 5; ++it) {
            int q = l + it * 64;
            if (q < 304) {
                int r = q >> 4, c0 = (q & 15) << 3;
                int rr = (r < 9) ? r : ((r < 16) ? r - 4 : r - 7);
                U8 rot; rot.v = *(uint4*)((char*)s_rot[w] + ((r * 256 + c0 * 2) ^ ((r & 7) << 4)));
                U8 rd;  rd.v  = *(const uint4*)(rp + rr * 128 + c0);
                U8 o;
                #pragma unroll
                for (int j = 0; j < 8; ++j) o.s[j] = f2b(b2f(rot.s[j]) * b2f(rd.s[j]));
                *(uint4*)(xp + q * 8) = o.v;
            }
        }
    } else {
        #pragma unroll
        for (int it = 0; it < 5; ++it) {
            int q = l + it * 64;
            if (q < 304) *(uint4*)(xp + q * 8) = (uint4){0, 0, 0, 0};
        }
    }
}

// ---------------- gate application (in-place on Zr, vectorized 8-wide) ----------------
__global__ __launch_bounds__(256)
void k_gate(short* __restrict__ Zr, long nitems)
{
    long idx = (long)blockIdx.x * 256 + threadIdx.x;
    if (idx >= nitems) return;
    long e = idx / 152;
    int jg = (int)(idx - e * 152);
    int j = jg * 8;
    short* rp = Zr + e * 1536;
    U8 z; z.v = *(const uint4*)(rp + j);
    U8 o;
    if (j < 320) {
        int rr = j >> 6;
        if (rr == 0) {
            #pragma unroll
            for (int q = 0; q < 8; ++q) o.s[q] = f2b(silu_(b2f(z.s[q])));
        } else {
            U8 g; g.v = *(const uint4*)(rp + 1216 + (rr - 1) * 64 + (j & 63));
            #pragma unroll
            for (int q = 0; q < 8; ++q) o.s[q] = f2b(b2f(z.s[q]) * b2f(g.s[q]));
        }
    } else if (j < 832) {
        U8 g; g.v = *(const uint4*)(rp + 1216 + ((j - 320) & 255));
        #pragma unroll
        for (int q = 0; q < 8; ++q) o.s[q] = f2b(b2f(z.s[q]) * b2f(g.s[q]));
    } else {
        int gi = j - 832; if (gi >= 192) gi -= 192;
        U8 g; g.v = *(const uint4*)(rp + 1280 + gi);
        #pragma unroll
        for (int q = 0; q < 8; ++q) o.s[q] = f2b(b2f(z.s[q]) * b2f(g.s[q]));
    }
    *(uint4*)(rp + j) = o.v;
}

// ---------------- LDS-free register GEMM: one wave per 64x64 output tile -------------
// A rows [rb, rb+64) x K, W cols [cbase, cbase+64) x K, both read as 16B fragments
// straight from global (L2-hot via XCD pinning). acc[4][4], 8 loads + 16 MFMA / 64-K.
// EPI: 0 raw | 1 +bias | 2 conv1-m0 (bias; jj<320 raw, else sigmoid->gates slot)
template<int Km, int Nreal, int EPI>
__device__ __forceinline__ void gemm_wave(
    const short* __restrict__ A, const long RS,
    const short* __restrict__ W, const float* __restrict__ bias,
    short* __restrict__ O, const long OS, const int oofs,
    const long rb, const int cbase)
{
    const int l = threadIdx.x & 63, l15 = l & 15, lhi = l >> 4;

    f32x4 acc[4][4];
    #pragma unroll
    for (int mt = 0; mt < 4; ++mt)
        #pragma unroll
        for (int nt = 0; nt < 4; ++nt)
            acc[mt][nt] = (f32x4){0.f, 0.f, 0.f, 0.f};

    const short* Ab = A + (rb + l15) * RS + lhi * 8;            // + mt*16*RS + kc
    const short* Wb = W + (long)(cbase + l15) * Km + lhi * 8;   // + nt*16*Km + kc

    constexpr int NCH = Km / 64;
    #pragma unroll 2
    for (int ch = 0; ch < NCH; ++ch) {
        const int kc = ch * 64;
        bf16x8 af[4], bf[4];
        #pragma unroll
        for (int mt = 0; mt < 4; ++mt)
            af[mt] = *(const bf16x8*)(Ab + (long)mt * 16 * RS + kc);
        #pragma unroll
        for (int nt = 0; nt < 4; ++nt)
            bf[nt] = *(const bf16x8*)(Wb + (long)nt * 16 * Km + kc);
        #pragma unroll
        for (int ks = 0; ks < 2; ++ks) {
            // second k-half fragments (k offset 32) loaded in the same batch:
            // reuse af/bf by loading 8 elems at kc + ks*... -> issue both halves up front
            if (ks == 1) {
                #pragma unroll
                for (int mt = 0; mt < 4; ++mt)
                    af[mt] = *(const bf16x8*)(Ab + (long)mt * 16 * RS + kc + 32);
                #pragma unroll
                for (int nt = 0; nt < 4; ++nt)
                    bf[nt] = *(const bf16x8*)(Wb + (long)nt * 16 * Km + kc + 32);
            }
            #pragma unroll
            for (int mt = 0; mt < 4; ++mt)
                #pragma unroll
                for (int nt = 0; nt < 4; ++nt)
                    acc[mt][nt] = __builtin_amdgcn_mfma_f32_16x16x32_bf16(af[mt], bf[nt], acc[mt][nt], 0, 0, 0);
        }
    }

    #pragma unroll
    for (int nt = 0; nt < 4; ++nt) {
        int jj = cbase + nt * 16 + l15;
        if (jj < Nreal) {
            float b = (EPI >= 1) ? bias[jj] : 0.f;
            #pragma unroll
            for (int mt = 0; mt < 4; ++mt)
                #pragma unroll
                for (int r = 0; r < 4; ++r) {
                    long e = rb + mt * 16 + lhi * 4 + r;
                    float v = acc[mt][nt][r] + b;
                    if constexpr (EPI == 2) {
                        if (jj < 320) O[e * OS + jj] = (short)f2b(v);
                        else          O[e * OS + 1216 + (jj - 320)] = (short)f2b(sigm_(v));
                    } else {
                        O[e * OS + oofs + jj] = (short)f2b(v);
                    }
                }
        }
    }
}

// ---------------- conv1: 64-thr wave-blocks, XCD-pinned; 13 phases x 4 quads --------
// bid -> xcd = bid&7, s = bid>>3; unit u = s%52 (ph = u>>2, wq = u&3), et = xcd+8*(s/52)
__global__ __launch_bounds__(64)
void k_conv1(const short* __restrict__ X, const short* __restrict__ W0,
             const short* __restrict__ W1, const short* __restrict__ W2,
             const float* __restrict__ b1m0, short* __restrict__ Zr, int nbt)
{
    const int bid = blockIdx.x;
    const int s = bid >> 3;
    const int et = (bid & 7) + ((s / 52) << 3);
    const int u = s % 52;
    const int ph = u >> 2, wq = u & 3;
    if (et >= nbt) return;
    const long rb = (long)et * 128 + (wq & 1) * 64;
    if (ph < 5) {
        const int cbase = (ph << 7) + (wq >> 1) * 64;
        gemm_wave< 640, 576, 2>(X,        2432, W0, b1m0,   Zr, 1536, 0,   rb, cbase);
    } else if (ph < 9) {
        const int cbase = ((ph - 5) << 7) + (wq >> 1) * 64;
        gemm_wave<1024, 512, 0>(X + 640,  2432, W1, nullptr, Zr, 1536, 320, rb, cbase);
    } else {
        const int cbase = ((ph - 9) << 7) + (wq >> 1) * 64;
        gemm_wave< 768, 384, 0>(X + 1664, 2432, W2, nullptr, Zr, 1536, 832, rb, cbase);
    }
}

// ---------------- conv2: 64-thr wave-blocks, XCD-pinned; 11 phases x 4 quads --------
__global__ __launch_bounds__(64)
void k_conv2(const short* __restrict__ Zr, const short* __restrict__ V0,
             const short* __restrict__ V1, const short* __restrict__ V2,
             const float* __restrict__ b2m0, short* __restrict__ Y2, int nbt)
{
    const int bid = blockIdx.x;
    const int s = bid >> 3;
    const int et = (bid & 7) + ((s / 44) << 3);
    const int u = s % 44;
    const int ph = u >> 2, wq = u & 3;
    if (et >= nbt) return;
    const long rb = (long)et * 128 + (wq & 1) * 64;
    if (ph < 3) {
        const int cbase = (ph << 7) + (wq >> 1) * 64;
        gemm_wave<320, 320, 1>(Zr,       1536, V0, b2m0,   Y2, 1216, 0,   rb, cbase);
    } else if (ph < 7) {
        const int cbase = ((ph - 3) << 7) + (wq >> 1) * 64;
        gemm_wave<512, 512, 0>(Zr + 320, 1536, V1, nullptr, Y2, 1216, 320, rb, cbase);
    } else {
        const int cbase = ((ph - 7) << 7) + (wq >> 1) * 64;
        gemm_wave<384, 384, 0>(Zr + 832, 1536, V2, nullptr, Y2, 1216, 832, rb, cbase);
    }
}

// ---------------- node-major wigner_inv + envelope + segment sum ----------------
__global__ __launch_bounds__(256)
void k_invn(const short* __restrict__ Y2, const float* __restrict__ winv,
            const float* __restrict__ env, const int* __restrict__ cnt,
            const int* __restrict__ off, const int* __restrict__ perm,
            float* __restrict__ out, long e0)
{
    __shared__ __align__(16) short s_y[2][1216];
    __shared__ float s_wv[2][476];
    const int t = threadIdx.x;
    const int n = blockIdx.x;
    const int deg = cnt[n], start = off[n];

    float acc[7];
    #pragma unroll
    for (int j = 0; j < 7; ++j) acc[j] = 0.f;

    auto stage = [&](int i, int b) {
        int el = perm[start + i];
        long ge = e0 + el;
        if (t < 152) ((uint4*)s_y[b])[t] = *(const uint4*)(Y2 + (long)el * 1216 + t * 8);
        for (int p = t; p < 475; p += 256) s_wv[b][p] = winv[ge * 475 + p];
        if (t == 0) s_wv[b][475] = env[ge];
    };

    if (deg > 0) stage(0, 0);
    for (int i = 0; i < deg; ++i) {
        __syncthreads();
        if (i + 1 < deg) stage(i + 1, (i + 1) & 1);
        const short* sy = s_y[i & 1];
        const float* sw = s_wv[i & 1];
        float ev = sw[475];
        #pragma unroll
        for (int j = 0; j < 7; ++j) {
            int f = t + j * 256;
            if (f < 1600) {
                int r = f >> 6, c = f & 63;
                float a = 0.f;
                #pragma unroll
                for (int k = 0; k < 19; ++k)
                    a = fmaf(sw[r * 19 + k], b2f((unsigned short)sy[k * 64 + c]), a);
                acc[j] = fmaf(a, ev, acc[j]);
            }
        }
    }
    #pragma unroll
    for (int j = 0; j < 7; ++j) {
        int f = t + j * 256;
        if (f < 1600) out[(long)n * 1600 + f] += acc[j];
    }
}

extern "C" void kernel_launch(void* const* d_in, const int* in_sizes, int n_in,
                              void* d_out, int out_size, void* d_ws, size_t ws_size,
                              hipStream_t stream)
{
    const float* nf   = (const float*)d_in[0];
    const float* ee   = (const float*)d_in[1];
    const float* wig  = (const float*)d_in[2];
    const float* winv = (const float*)d_in[3];
    const float* env  = (const float*)d_in[4];
    const float* rw1  = (const float*)d_in[5];
    const float* rb1  = (const float*)d_in[6];
    const float* rw2  = (const float*)d_in[7];
    const float* rb2  = (const float*)d_in[8];
    const float* w1m0 = (const float*)d_in[9];
    const float* b1m0 = (const float*)d_in[10];
    const float* w1r1 = (const float*)d_in[11];
    const float* w1i1 = (const float*)d_in[12];
    const float* w1r2 = (const float*)d_in[13];
    const float* w1i2 = (const float*)d_in[14];
    const float* w2m0 = (const float*)d_in[15];
    const float* b2m0 = (const float*)d_in[16];
    const float* w2r1 = (const float*)d_in[17];
    const float* w2i1 = (const float*)d_in[18];
    const float* w2r2 = (const float*)d_in[19];
    const float* w2i2 = (const float*)d_in[20];
    const int*   snd  = (const int*)d_in[21];
    const int*   rcv  = (const int*)d_in[22];
    float* out = (float*)d_out;

    const long E = in_sizes[21];

    short* Wb  = (short*)d_ws;
    short* nfT = Wb + W_TOTAL;
    int* cnt   = (int*)(nfT + NFT_ELEMS);
    int* off   = cnt + 2512;
    int* nxt   = off + 2512;
    int* perm  = nxt + 2512;

    // per-edge ws: perm 4B + X 4864B (X -> Y2) + Rc 3072B (rad -> Zraw+gates)
    const size_t fixed = (size_t)W_TOTAL * 2 + (size_t)NFT_ELEMS * 2 + 3 * 2512 * 4;
    long cap = (ws_size > fixed) ? (long)((ws_size - fixed) / 7940) : 128;
    long chunk = (cap / 128) * 128;
    if (chunk < 128) chunk = 128;
    long Epad = ((E + 127) / 128) * 128;
    if (chunk > Epad) chunk = Epad;

    short* Xc = (short*)(perm + chunk);     // chunk*2432
    short* Rc = Xc + chunk * 2432;          // chunk*1536

    hipMemsetAsync(d_out, 0, (size_t)out_size * sizeof(float), stream);
    k_prep<<<(int)((W_TOTAL + 511) / 512), 512, 0, stream>>>(
        w1m0, w1r1, w1i1, w1r2, w1i2, w2m0, w2r1, w2i1, w2r2, w2i2, rw2, Wb);
    k_nft<<<NNODES, 256, 0, stream>>>(nf, nfT);

    for (long base = 0; base < E; base += chunk) {
        long n = E - base; if (n > chunk) n = chunk;
        int nb2 = (int)((n + 127) / 128);
        int nb8 = ((nb2 + 7) / 8) * 8;
        int nbe = (int)((n + 255) / 256);

        hipMemsetAsync(cnt, 0, NNODES * sizeof(int), stream);
        k_hist<<<nbe, 256, 0, stream>>>(rcv, cnt, base, n);
        k_scan<<<1, 256, 0, stream>>>(cnt, off, nxt);
        k_scat<<<nbe, 256, 0, stream>>>(rcv, nxt, perm, base, n);

        k_rad <<<(int)((n + 31) / 32), 512, 0, stream>>>(ee, rw1, rb1, rb2, Wb + OFF_RW2T, Rc, base, E);
        k_rot2<<<nb2 * 32, 256, 0, stream>>>(wig, nfT, Rc, snd, rcv, Xc, base, n);

        k_conv1<<<nb8 * 52, 64, 0, stream>>>(Xc, Wb + OFF_W1T, Wb + OFF_W1C1, Wb + OFF_W1C2, b1m0, Rc, nb2);

        long nitems = (long)nb2 * 128 * 152;
        k_gate<<<(int)((nitems + 255) / 256), 256, 0, stream>>>(Rc, nitems);

        k_conv2<<<nb8 * 44, 64, 0, stream>>>(Rc, Wb + OFF_V0T, Wb + OFF_V1C, Wb + OFF_V2C, b2m0, Xc, nb2);

        k_invn<<<NNODES, 256, 0, stream>>>(Xc, winv, env, cnt, off, perm, out, base);
    }
    (void)n_in;
}

// Round 15
// 1033.945 us; speedup vs baseline: 1.3599x; 1.3599x over previous
//
#include <hip/hip_runtime.h>

// SO(2)-equivariant edge conv — bf16 MFMA pipeline, round 15.
// X per edge (2432 bf16): m0 rows0-4 [0,640) | m1 re+im [640,1664) | m2 [1664,2432)
// Zr per edge (1536-short stride): conv1 out [0,1216) + sigmoid gates [1216,1472)
// Y2 per edge (1216 bf16). Weights transposed [N][K] bf16, N padded to 128, complex folded.
// r15: revert r14; conv tiles widened to 128x256 (8 waves/512 thr, N-phases 13->7 and
// 11->6) -> A re-fetch traffic /1.9 and 16 waves/CU (2x r13). Staging keeps r13's
// coalesced slot permutation; single-buffered 48KB LDS, 2 barriers/64-K chunk.

typedef __attribute__((ext_vector_type(8))) short bf16x8;
typedef __attribute__((ext_vector_type(4))) float f32x4;

union U8 { uint4 v; unsigned short s[8]; };

__device__ __forceinline__ unsigned short f2b(float f) {
    unsigned u = __float_as_uint(f);
    unsigned r = (u + 0x7FFFu + ((u >> 16) & 1u)) >> 16;
    return (unsigned short)r;
}
__device__ __forceinline__ float b2f(unsigned short h) {
    return __uint_as_float(((unsigned)h) << 16);
}
__device__ __forceinline__ float sigm_(float x){ return 1.0f/(1.0f+__expf(-x)); }
__device__ __forceinline__ float silu_(float x){ return x/(1.0f+__expf(-x)); }

// async global->LDS DMA, 16B per lane; lds base wave-uniform, global source per-lane
__device__ __forceinline__ void async16(short* lds, const short* g) {
    __builtin_amdgcn_global_load_lds(
        (const __attribute__((address_space(1))) void*)g,
        (__attribute__((address_space(3))) void*)lds, 16, 0, 0);
}

// weight region offsets (bf16 elems) in ws — N padded to multiples of 128
#define OFF_W1T   0L         // [640][640]  real N=576
#define OFF_W1C1  409600L    // [512][1024]
#define OFF_W1C2  933888L    // [512][768]  real N=384
#define OFF_V0T   1327104L   // [384][320]  real N=320
#define OFF_V1C   1449984L   // [512][512]
#define OFF_V2C   1712128L   // [512][384]  real N=384
#define OFF_RW2T  1908736L   // [1536][64]
#define W_TOTAL   2007040L
#define NNODES    2500
#define NFT_ELEMS (2500L * 2048L)

// ---------------- weight prep: f32 -> bf16, transpose [N][K], fold complex, pad N ----
__global__ void k_prep(const float* __restrict__ w1m0, const float* __restrict__ w1r1,
                       const float* __restrict__ w1i1, const float* __restrict__ w1r2,
                       const float* __restrict__ w1i2, const float* __restrict__ w2m0,
                       const float* __restrict__ w2r1, const float* __restrict__ w2i1,
                       const float* __restrict__ w2r2, const float* __restrict__ w2i2,
                       const float* __restrict__ rw2, short* __restrict__ W)
{
    long i = (long)blockIdx.x * blockDim.x + threadIdx.x;
    if (i >= W_TOTAL) return;
    float v;
    if (i < OFF_W1C1) {                    // W1T [640][640] real 576
        int n = (int)(i / 640), k = (int)(i % 640);
        v = (n < 576) ? w1m0[k * 576 + n] : 0.f;
    } else if (i < OFF_W1C2) {             // W1c1 [512][1024]
        long j = i - OFF_W1C1; int n = (int)(j >> 10), k = (int)(j & 1023);
        v = (n < 256) ? ((k < 512) ? w1r1[k*256 + n] : -w1i1[(k-512)*256 + n])
                      : ((k < 512) ? w1i1[k*256 + (n-256)] : w1r1[(k-512)*256 + (n-256)]);
    } else if (i < OFF_V0T) {              // W1c2 [512][768] real 384
        long j = i - OFF_W1C2; int n = (int)(j / 768), k = (int)(j % 768);
        v = (n >= 384) ? 0.f
          : (n < 192) ? ((k < 384) ? w1r2[k*192 + n] : -w1i2[(k-384)*192 + n])
                      : ((k < 384) ? w1i2[k*192 + (n-192)] : w1r2[(k-384)*192 + (n-192)]);
    } else if (i < OFF_V1C) {              // V0T [384][320] real 320
        long j = i - OFF_V0T; int n = (int)(j / 320), k = (int)(j % 320);
        v = (n < 320) ? w2m0[k * 320 + n] : 0.f;
    } else if (i < OFF_V2C) {              // V1c [512][512]
        long j = i - OFF_V1C; int n = (int)(j >> 9), k = (int)(j & 511);
        v = (n < 256) ? ((k < 256) ? w2r1[k*256 + n] : -w2i1[(k-256)*256 + n])
                      : ((k < 256) ? w2i1[k*256 + (n-256)] : w2r1[(k-256)*256 + (n-256)]);
    } else if (i < OFF_RW2T) {             // V2c [512][384] real 384
        long j = i - OFF_V2C; int n = (int)(j / 384), k = (int)(j % 384);
        v = (n >= 384) ? 0.f
          : (n < 192) ? ((k < 192) ? w2r2[k*192 + n] : -w2i2[(k-192)*192 + n])
                      : ((k < 192) ? w2i2[k*192 + (n-192)] : w2r2[(k-192)*192 + (n-192)]);
    } else {                               // RW2T [1536][64]
        long j = i - OFF_RW2T; int n = (int)(j >> 6), d = (int)(j & 63);
        v = rw2[d * 1536 + n];
    }
    W[i] = (short)f2b(v);
}

// ---------------- node-feature transpose ----------------
__global__ __launch_bounds__(256)
void k_nft(const float* __restrict__ nf, short* __restrict__ nfT)
{
    __shared__ float s_nf[25 * 65];
    const int t = threadIdx.x;
    const long nn = blockIdx.x;
    for (int p = t; p < 1600; p += 256) {
        int r = p >> 6, c = p & 63;
        s_nf[r * 65 + c] = nf[nn * 1600 + p];
    }
    __syncthreads();
    for (int i = t; i < 2048; i += 256) {
        int c = i >> 5, k = i & 31;
        float v = (k < 25) ? s_nf[k * 65 + c] : 0.f;
        nfT[nn * 2048 + i] = (short)f2b(v);
    }
}

// ---------------- CSR build ----------------
__global__ void k_hist(const int* __restrict__ rcv, int* __restrict__ cnt, long e0, long n)
{
    long e = (long)blockIdx.x * 256 + threadIdx.x;
    if (e < n) atomicAdd(&cnt[rcv[e0 + e]], 1);
}

__global__ __launch_bounds__(256)
void k_scan(const int* __restrict__ cnt, int* __restrict__ off, int* __restrict__ nxt)
{
    __shared__ int part[256];
    const int t = threadIdx.x;
    const int base = t * 10;
    int loc[10]; int s = 0;
    #pragma unroll
    for (int j = 0; j < 10; ++j) {
        int idx = base + j;
        int v = (idx < NNODES) ? cnt[idx] : 0;
        loc[j] = s; s += v;
    }
    part[t] = s;
    __syncthreads();
    for (int d = 1; d < 256; d <<= 1) {
        int v = part[t];
        int u = (t >= d) ? part[t - d] : 0;
        __syncthreads();
        part[t] = v + u;
        __syncthreads();
    }
    int excl = (t == 0) ? 0 : part[t - 1];
    #pragma unroll
    for (int j = 0; j < 10; ++j) {
        int idx = base + j;
        if (idx < NNODES) { int o = excl + loc[j]; off[idx] = o; nxt[idx] = o; }
    }
}

__global__ void k_scat(const int* __restrict__ rcv, int* __restrict__ nxt,
                       int* __restrict__ perm, long e0, long n)
{
    long e = (long)blockIdx.x * 256 + threadIdx.x;
    if (e < n) {
        int p = atomicAdd(&nxt[rcv[e0 + e]], 1);
        perm[p] = (int)e;
    }
}

// ---------------- radial MLP ----------------
__global__ __launch_bounds__(512)
void k_rad(const float* __restrict__ ee, const float* __restrict__ rw1,
           const float* __restrict__ rb1, const float* __restrict__ rb2,
           const short* __restrict__ RW2T, short* __restrict__ rad,
           long e0, long Etot)
{
    __shared__ __align__(16) short s_h[32 * 64];
    const int t = threadIdx.x, w = t >> 6, l = t & 63, l15 = l & 15, lhi = l >> 4;
    const long eb = (long)blockIdx.x * 32;

    #pragma unroll
    for (int j = 0; j < 4; ++j) {
        int i = t + j * 512;
        int e = i >> 6, d = i & 63;
        long ge = e0 + eb + e;
        float a = rb1[d];
        if (ge < Etot) {
            const float* ep = ee + ge * 128;
            #pragma unroll 16
            for (int dd = 0; dd < 128; ++dd) a = fmaf(ep[dd], rw1[dd * 64 + d], a);
            a = silu_(a);
        } else a = 0.f;
        *(short*)((char*)s_h + e * 128 + ((d * 2) ^ ((e & 7) << 4))) = (short)f2b(a);
    }
    __syncthreads();

    f32x4 acc[6][2][2];
    #pragma unroll
    for (int g = 0; g < 6; ++g)
        #pragma unroll
        for (int mt = 0; mt < 2; ++mt)
            #pragma unroll
            for (int nt = 0; nt < 2; ++nt)
                acc[g][mt][nt] = (f32x4){0.f, 0.f, 0.f, 0.f};

    #pragma unroll
    for (int ks = 0; ks < 2; ++ks) {
        bf16x8 af[2];
        #pragma unroll
        for (int mt = 0; mt < 2; ++mt)
            af[mt] = *(const bf16x8*)((const char*)s_h + (mt * 16 + l15) * 128 +
                                      (((ks << 6) + (lhi << 4)) ^ ((l & 7) << 4)));
        #pragma unroll
        for (int g = 0; g < 6; ++g) {
            int grp = w + g * 8;
            #pragma unroll
            for (int nt = 0; nt < 2; ++nt) {
                int col = grp * 32 + nt * 16 + l15;
                bf16x8 bf = *(const bf16x8*)(RW2T + (long)col * 64 + (ks << 5) + (lhi << 3));
                #pragma unroll
                for (int mt = 0; mt < 2; ++mt)
                    acc[g][mt][nt] = __builtin_amdgcn_mfma_f32_16x16x32_bf16(af[mt], bf, acc[g][mt][nt], 0, 0, 0);
            }
        }
    }
    #pragma unroll
    for (int g = 0; g < 6; ++g)
        #pragma unroll
        for (int nt = 0; nt < 2; ++nt) {
            int col = (w + g * 8) * 32 + nt * 16 + l15;
            float bias = rb2[col];
            #pragma unroll
            for (int mt = 0; mt < 2; ++mt)
                #pragma unroll
                for (int r = 0; r < 4; ++r) {
                    int e = mt * 16 + lhi * 4 + r;
                    rad[(eb + e) * 1536 + col] = (short)f2b(acc[g][mt][nt][r] + bias);
                }
        }
}

// ---------------- MFMA wigner rotate, vectorized writeout ----------------
__global__ __launch_bounds__(256)
void k_rot2(const float* __restrict__ wig, const short* __restrict__ nfT,
            const short* __restrict__ rad,
            const int* __restrict__ snd, const int* __restrict__ rcv,
            short* __restrict__ X, long e0, long nchunk)
{
    __shared__ float s_wg[4][480];
    __shared__ __align__(16) short s_rot[4][20 * 128];
    const int t = threadIdx.x, w = t >> 6, l = t & 63, l15 = l & 15, lhi = l >> 4;
    const long eb = (long)blockIdx.x * 4;
    const long el = eb + w;
    const bool valid = (el < nchunk);

    for (int p = t; p < 4 * 475; p += 256) {
        int e = p / 475, q = p - e * 475;
        if (eb + e < nchunk) s_wg[e][q] = wig[(e0 + eb + e) * 475 + q];
    }
    __syncthreads();

    if (valid) {
        long ge = e0 + el;
        int n0 = snd[ge], n1 = rcv[ge];
        U8 a0u, a1u;
        #pragma unroll
        for (int j = 0; j < 8; ++j) {
            int k = lhi * 8 + j;
            a0u.s[j] = (k < 25) ? f2b(s_wg[w][l15 * 25 + k]) : (unsigned short)0;
            a1u.s[j] = (l15 < 3 && k < 25) ? f2b(s_wg[w][(16 + l15) * 25 + k]) : (unsigned short)0;
        }
        bf16x8 a0 = *(bf16x8*)&a0u, a1 = *(bf16x8*)&a1u;

        f32x4 acc0[8], acc1[8];
        #pragma unroll
        for (int nt = 0; nt < 8; ++nt) {
            acc0[nt] = (f32x4){0.f, 0.f, 0.f, 0.f};
            acc1[nt] = (f32x4){0.f, 0.f, 0.f, 0.f};
        }
        #pragma unroll
        for (int nt = 0; nt < 8; ++nt) {
            int col = nt * 16 + l15;
            bf16x8 b = *(const bf16x8*)(nfT + (long)(col < 64 ? n0 : n1) * 2048 +
                                        (long)(col & 63) * 32 + (lhi << 3));
            acc0[nt] = __builtin_amdgcn_mfma_f32_16x16x32_bf16(a0, b, acc0[nt], 0, 0, 0);
            acc1[nt] = __builtin_amdgcn_mfma_f32_16x16x32_bf16(a1, b, acc1[nt], 0, 0, 0);
        }
        char* base = (char*)s_rot[w];
        #pragma unroll
        for (int nt = 0; nt < 8; ++nt) {
            int col2 = (nt * 16 + l15) * 2;
            #pragma unroll
            for (int r = 0; r < 4; ++r) {
                int row = lhi * 4 + r;
                *(short*)(base + ((row * 256 + col2) ^ ((row & 7) << 4))) = (short)f2b(acc0[nt][r]);
            }
            if (lhi == 0) {
                #pragma unroll
                for (int r = 0; r < 4; ++r) {
                    int row = 16 + r;
                    *(short*)(base + ((row * 256 + col2) ^ ((row & 7) << 4))) = (short)f2b(acc1[nt][r]);
                }
            }
        }
    }
    __syncthreads();

    short* xp = X + el * 2432;
    if (valid) {
        const short* rp = rad + el * 1536;
        #pragma unroll
        for (int it = 0; it < 5; ++it) {
            int q = l + it * 64;
            if (q < 304) {
                int r = q >> 4, c0 = (q & 15) << 3;
                int rr = (r < 9) ? r : ((r < 16) ? r - 4 : r - 7);
                U8 rot; rot.v = *(uint4*)((char*)s_rot[w] + ((r * 256 + c0 * 2) ^ ((r & 7) << 4)));
                U8 rd;  rd.v  = *(const uint4*)(rp + rr * 128 + c0);
                U8 o;
                #pragma unroll
                for (int j = 0; j < 8; ++j) o.s[j] = f2b(b2f(rot.s[j]) * b2f(rd.s[j]));
                *(uint4*)(xp + q * 8) = o.v;
            }
        }
    } else {
        #pragma unroll
        for (int it = 0; it < 5; ++it) {
            int q = l + it * 64;
            if (q < 304) *(uint4*)(xp + q * 8) = (uint4){0, 0, 0, 0};
        }
    }
}

// ---------------- gate application (in-place on Zr, vectorized 8-wide) ----------------
__global__ __launch_bounds__(256)
void k_gate(short* __restrict__ Zr, long nitems)
{
    long idx = (long)blockIdx.x * 256 + threadIdx.x;
    if (idx >= nitems) return;
    long e = idx / 152;
    int jg = (int)(idx - e * 152);
    int j = jg * 8;
    short* rp = Zr + e * 1536;
    U8 z; z.v = *(const uint4*)(rp + j);
    U8 o;
    if (j < 320) {
        int rr = j >> 6;
        if (rr == 0) {
            #pragma unroll
            for (int q = 0; q < 8; ++q) o.s[q] = f2b(silu_(b2f(z.s[q])));
        } else {
            U8 g; g.v = *(const uint4*)(rp + 1216 + (rr - 1) * 64 + (j & 63));
            #pragma unroll
            for (int q = 0; q < 8; ++q) o.s[q] = f2b(b2f(z.s[q]) * b2f(g.s[q]));
        }
    } else if (j < 832) {
        U8 g; g.v = *(const uint4*)(rp + 1216 + ((j - 320) & 255));
        #pragma unroll
        for (int q = 0; q < 8; ++q) o.s[q] = f2b(b2f(z.s[q]) * b2f(g.s[q]));
    } else {
        int gi = j - 832; if (gi >= 192) gi -= 192;
        U8 g; g.v = *(const uint4*)(rp + 1280 + gi);
        #pragma unroll
        for (int q = 0; q < 8; ++q) o.s[q] = f2b(b2f(z.s[q]) * b2f(g.s[q]));
    }
    *(uint4*)(rp + j) = o.v;
}

// ---------------- 128x256 GEMM body, BK=64, 8 waves (2M x 4N), coalesced staging ----
// LDS slot s (16B) holds (row = s>>3, k8 = (s&7)^(row&7)); DMA dest linear per wave,
// global src row-contiguous permuted; read XOR k8^(l&7) -> 2-way bank alias (free).
// EPI: 0 raw | 1 +bias | 2 conv1-m0 (bias; jj<320 raw, else sigmoid->gates slot)
template<int Km, int Nreal, int EPI>
__device__ __forceinline__ void gemm_body(
    const short* __restrict__ A, const long RS,
    const short* __restrict__ W, const float* __restrict__ bias,
    short* __restrict__ O, const long OS, const int oofs,
    short* __restrict__ sA, short* __restrict__ sB, const int et, const int cb)
{
    const int t = threadIdx.x, w = t >> 6, l = t & 63, l15 = l & 15, lhi = l >> 4;
    const int wm = w & 1, wn = w >> 1;      // M half, N quarter
    const long eb = (long)et * 128;
    const short* Ap = A + eb * RS;
    const short* Wp = W + (long)cb * Km;

    f32x4 acc[4][4];
    #pragma unroll
    for (int mt = 0; mt < 4; ++mt)
        #pragma unroll
        for (int nt = 0; nt < 4; ++nt)
            acc[mt][nt] = (f32x4){0.f, 0.f, 0.f, 0.f};

    // slot coords: s = i*512 + t -> row = s>>3, logical k8 = (s&7)^(row&7)
    int rowA[2], k8A[2];
    #pragma unroll
    for (int i = 0; i < 2; ++i) {
        int s = i * 512 + t;
        rowA[i] = s >> 3;
        k8A[i]  = (s & 7) ^ (rowA[i] & 7);
    }
    int rowB[4], k8B[4];
    #pragma unroll
    for (int i = 0; i < 4; ++i) {
        int s = i * 512 + t;
        rowB[i] = s >> 3;
        k8B[i]  = (s & 7) ^ (rowB[i] & 7);
    }
    const int wb = w << 6;                  // wave-uniform lane-block base (slots)

    const int rx = l & 7;
    constexpr int NCH = Km / 64;
    for (int ch = 0; ch < NCH; ++ch) {
        const int kc = ch * 64;
        __syncthreads();                    // all waves done reading previous chunk
        #pragma unroll
        for (int i = 0; i < 2; ++i)
            async16(sA + (i * 512 + wb) * 8, Ap + (long)rowA[i] * RS + kc + k8A[i] * 8);
        #pragma unroll
        for (int i = 0; i < 4; ++i)
            async16(sB + (i * 512 + wb) * 8, Wp + (long)rowB[i] * Km + kc + k8B[i] * 8);
        __syncthreads();                    // vmcnt drain -> tile populated
        #pragma unroll
        for (int ks = 0; ks < 2; ++ks) {
            const int ko = (((ks << 2) + lhi) ^ rx) << 3;
            bf16x8 af[4], bf[4];
            #pragma unroll
            for (int mt = 0; mt < 4; ++mt) {
                int row = wm * 64 + mt * 16 + l15;
                af[mt] = *(const bf16x8*)(sA + row * 64 + ko);
            }
            #pragma unroll
            for (int nt = 0; nt < 4; ++nt) {
                int row = wn * 64 + nt * 16 + l15;
                bf[nt] = *(const bf16x8*)(sB + row * 64 + ko);
            }
            #pragma unroll
            for (int mt = 0; mt < 4; ++mt)
                #pragma unroll
                for (int nt = 0; nt < 4; ++nt)
                    acc[mt][nt] = __builtin_amdgcn_mfma_f32_16x16x32_bf16(af[mt], bf[nt], acc[mt][nt], 0, 0, 0);
        }
    }

    const int r0 = wm * 64, c0 = wn * 64;
    #pragma unroll
    for (int nt = 0; nt < 4; ++nt) {
        int jj = cb + c0 + nt * 16 + l15;
        if (jj < Nreal) {
            float b = (EPI >= 1) ? bias[jj] : 0.f;
            #pragma unroll
            for (int mt = 0; mt < 4; ++mt)
                #pragma unroll
                for (int r = 0; r < 4; ++r) {
                    long e = eb + r0 + mt * 16 + lhi * 4 + r;
                    float v = acc[mt][nt][r] + b;
                    if constexpr (EPI == 2) {
                        if (jj < 320) O[e * OS + jj] = (short)f2b(v);
                        else          O[e * OS + 1216 + (jj - 320)] = (short)f2b(sigm_(v));
                    } else {
                        O[e * OS + oofs + jj] = (short)f2b(v);
                    }
                }
        }
    }
}

// ---------------- conv1: XCD-pinned 1-D grid, 7 N256-phases per edge-tile ----------
__global__ __launch_bounds__(512)
void k_conv1(const short* __restrict__ X, const short* __restrict__ W0,
             const short* __restrict__ W1, const short* __restrict__ W2,
             const float* __restrict__ b1m0, short* __restrict__ Zr, int nbt)
{
    __shared__ __align__(16) short sA[8192];     // 128 x 64
    __shared__ __align__(16) short sB[16384];    // 256 x 64
    const int bid = blockIdx.x;
    const int s = bid >> 3;
    const int et = (bid & 7) + ((s / 7) << 3);
    const int ph = s % 7;
    if (et >= nbt) return;
    if (ph < 3)
        gemm_body< 640, 576, 2>(X,        2432, W0, b1m0,   Zr, 1536, 0,   sA, sB, et, ph << 8);
    else if (ph < 5)
        gemm_body<1024, 512, 0>(X + 640,  2432, W1, nullptr, Zr, 1536, 320, sA, sB, et, (ph - 3) << 8);
    else
        gemm_body< 768, 384, 0>(X + 1664, 2432, W2, nullptr, Zr, 1536, 832, sA, sB, et, (ph - 5) << 8);
}

// ---------------- conv2: XCD-pinned 1-D grid, 6 N256-phases per edge-tile ----------
__global__ __launch_bounds__(512)
void k_conv2(const short* __restrict__ Zr, const short* __restrict__ V0,
             const short* __restrict__ V1, const short* __restrict__ V2,
             const float* __restrict__ b2m0, short* __restrict__ Y2, int nbt)
{
    __shared__ __align__(16) short sA[8192];
    __shared__ __align__(16) short sB[16384];
    const int bid = blockIdx.x;
    const int s = bid >> 3;
    const int et = (bid & 7) + ((s / 6) << 3);
    const int ph = s % 6;
    if (et >= nbt) return;
    if (ph < 2)
        gemm_body<320, 320, 1>(Zr,       1536, V0, b2m0,   Y2, 1216, 0,   sA, sB, et, ph << 8);
    else if (ph < 4)
        gemm_body<512, 512, 0>(Zr + 320, 1536, V1, nullptr, Y2, 1216, 320, sA, sB, et, (ph - 2) << 8);
    else
        gemm_body<384, 384, 0>(Zr + 832, 1536, V2, nullptr, Y2, 1216, 832, sA, sB, et, (ph - 4) << 8);
}

// ---------------- node-major wigner_inv + envelope + segment sum ----------------
__global__ __launch_bounds__(256)
void k_invn(const short* __restrict__ Y2, const float* __restrict__ winv,
            const float* __restrict__ env, const int* __restrict__ cnt,
            const int* __restrict__ off, const int* __restrict__ perm,
            float* __restrict__ out, long e0)
{
    __shared__ __align__(16) short s_y[2][1216];
    __shared__ float s_wv[2][476];
    const int t = threadIdx.x;
    const int n = blockIdx.x;
    const int deg = cnt[n], start = off[n];

    float acc[7];
    #pragma unroll
    for (int j = 0; j < 7; ++j) acc[j] = 0.f;

    auto stage = [&](int i, int b) {
        int el = perm[start + i];
        long ge = e0 + el;
        if (t < 152) ((uint4*)s_y[b])[t] = *(const uint4*)(Y2 + (long)el * 1216 + t * 8);
        for (int p = t; p < 475; p += 256) s_wv[b][p] = winv[ge * 475 + p];
        if (t == 0) s_wv[b][475] = env[ge];
    };

    if (deg > 0) stage(0, 0);
    for (int i = 0; i < deg; ++i) {
        __syncthreads();
        if (i + 1 < deg) stage(i + 1, (i + 1) & 1);
        const short* sy = s_y[i & 1];
        const float* sw = s_wv[i & 1];
        float ev = sw[475];
        #pragma unroll
        for (int j = 0; j < 7; ++j) {
            int f = t + j * 256;
            if (f < 1600) {
                int r = f >> 6, c = f & 63;
                float a = 0.f;
                #pragma unroll
                for (int k = 0; k < 19; ++k)
                    a = fmaf(sw[r * 19 + k], b2f((unsigned short)sy[k * 64 + c]), a);
                acc[j] = fmaf(a, ev, acc[j]);
            }
        }
    }
    #pragma unroll
    for (int j = 0; j < 7; ++j) {
        int f = t + j * 256;
        if (f < 1600) out[(long)n * 1600 + f] += acc[j];
    }
}

extern "C" void kernel_launch(void* const* d_in, const int* in_sizes, int n_in,
                              void* d_out, int out_size, void* d_ws, size_t ws_size,
                              hipStream_t stream)
{
    const float* nf   = (const float*)d_in[0];
    const float* ee   = (const float*)d_in[1];
    const float* wig  = (const float*)d_in[2];
    const float* winv = (const float*)d_in[3];
    const float* env  = (const float*)d_in[4];
    const float* rw1  = (const float*)d_in[5];
    const float* rb1  = (const float*)d_in[6];
    const float* rw2  = (const float*)d_in[7];
    const float* rb2  = (const float*)d_in[8];
    const float* w1m0 = (const float*)d_in[9];
    const float* b1m0 = (const float*)d_in[10];
    const float* w1r1 = (const float*)d_in[11];
    const float* w1i1 = (const float*)d_in[12];
    const float* w1r2 = (const float*)d_in[13];
    const float* w1i2 = (const float*)d_in[14];
    const float* w2m0 = (const float*)d_in[15];
    const float* b2m0 = (const float*)d_in[16];
    const float* w2r1 = (const float*)d_in[17];
    const float* w2i1 = (const float*)d_in[18];
    const float* w2r2 = (const float*)d_in[19];
    const float* w2i2 = (const float*)d_in[20];
    const int*   snd  = (const int*)d_in[21];
    const int*   rcv  = (const int*)d_in[22];
    float* out = (float*)d_out;

    const long E = in_sizes[21];

    short* Wb  = (short*)d_ws;
    short* nfT = Wb + W_TOTAL;
    int* cnt   = (int*)(nfT + NFT_ELEMS);
    int* off   = cnt + 2512;
    int* nxt   = off + 2512;
    int* perm  = nxt + 2512;

    // per-edge ws: perm 4B + X 4864B (X -> Y2) + Rc 3072B (rad -> Zraw+gates)
    const size_t fixed = (size_t)W_TOTAL * 2 + (size_t)NFT_ELEMS * 2 + 3 * 2512 * 4;
    long cap = (ws_size > fixed) ? (long)((ws_size - fixed) / 7940) : 128;
    long chunk = (cap / 128) * 128;
    if (chunk < 128) chunk = 128;
    long Epad = ((E + 127) / 128) * 128;
    if (chunk > Epad) chunk = Epad;

    short* Xc = (short*)(perm + chunk);     // chunk*2432
    short* Rc = Xc + chunk * 2432;          // chunk*1536

    hipMemsetAsync(d_out, 0, (size_t)out_size * sizeof(float), stream);
    k_prep<<<(int)((W_TOTAL + 511) / 512), 512, 0, stream>>>(
        w1m0, w1r1, w1i1, w1r2, w1i2, w2m0, w2r1, w2i1, w2r2, w2i2, rw2, Wb);
    k_nft<<<NNODES, 256, 0, stream>>>(nf, nfT);

    for (long base = 0; base < E; base += chunk) {
        long n = E - base; if (n > chunk) n = chunk;
        int nb2 = (int)((n + 127) / 128);
        int nb8 = ((nb2 + 7) / 8) * 8;
        int nbe = (int)((n + 255) / 256);

        hipMemsetAsync(cnt, 0, NNODES * sizeof(int), stream);
        k_hist<<<nbe, 256, 0, stream>>>(rcv, cnt, base, n);
        k_scan<<<1, 256, 0, stream>>>(cnt, off, nxt);
        k_scat<<<nbe, 256, 0, stream>>>(rcv, nxt, perm, base, n);

        k_rad <<<(int)((n + 31) / 32), 512, 0, stream>>>(ee, rw1, rb1, rb2, Wb + OFF_RW2T, Rc, base, E);
        k_rot2<<<nb2 * 32, 256, 0, stream>>>(wig, nfT, Rc, snd, rcv, Xc, base, n);

        k_conv1<<<nb8 * 7, 512, 0, stream>>>(Xc, Wb + OFF_W1T, Wb + OFF_W1C1, Wb + OFF_W1C2, b1m0, Rc, nb2);

        long nitems = (long)nb2 * 128 * 152;
        k_gate<<<(int)((nitems + 255) / 256), 256, 0, stream>>>(Rc, nitems);

        k_conv2<<<nb8 * 6, 512, 0, stream>>>(Rc, Wb + OFF_V0T, Wb + OFF_V1C, Wb + OFF_V2C, b2m0, Xc, nb2);

        k_invn<<<NNODES, 256, 0, stream>>>(Xc, winv, env, cnt, off, perm, out, base);
    }
    (void)n_in;
}